// Round 1
// baseline (59.866 us; speedup 1.0000x reference)
//
#include <hip/hip_runtime.h>

// 4-bit comparator over float-encoded bits (values exactly 0.0 or 1.0).
// A,B: [N,4] float32 (MSB first). Outputs: gt [N], eq [N], concatenated in d_out.
// Pure streaming: 32 B in + 8 B out per row -> memory-bound.

__global__ __launch_bounds__(256) void cmp4_kernel(
    const float4* __restrict__ A, const float4* __restrict__ B,
    float* __restrict__ out_gt, float* __restrict__ out_eq, int n)
{
    int i = blockIdx.x * blockDim.x + threadIdx.x;
    if (i >= n) return;

    float4 a = A[i];
    float4 b = B[i];

    // MSB first: a.x=a3, a.y=a2, a.z=a1, a.w=a0
    float a3 = a.x, a2 = a.y, a1 = a.z, a0 = a.w;
    float b3 = b.x, b2 = b.y, b1 = b.z, b0 = b.w;

    // eq_k = NOT(XOR(a,b)) = 1 - (a + b - 2ab)
    float eq3 = 1.0f - (a3 + b3 - 2.0f * a3 * b3);
    float eq2 = 1.0f - (a2 + b2 - 2.0f * a2 * b2);
    float eq1 = 1.0f - (a1 + b1 - 2.0f * a1 * b1);
    float eq0 = 1.0f - (a0 + b0 - 2.0f * a0 * b0);

    // gt_k = a AND NOT b = a * (1 - b)
    float gt3 = a3 * (1.0f - b3);
    float gt2 = a2 * (1.0f - b2);
    float gt1 = a1 * (1.0f - b1);
    float gt0 = a0 * (1.0f - b0);

    float eq32  = eq3 * eq2;
    float eq321 = eq32 * eq1;

    float term2 = eq3 * gt2;
    float term3 = eq32 * gt1;
    float term4 = eq321 * gt0;

    // OR(a,b) = a + b - ab
    float t12   = gt3 + term2 - gt3 * term2;
    float t123  = t12 + term3 - t12 * term3;
    float a_gt_b = t123 + term4 - t123 * term4;

    float a_eq_b = eq321 * eq0;

    out_gt[i] = a_gt_b;
    out_eq[i] = a_eq_b;
}

extern "C" void kernel_launch(void* const* d_in, const int* in_sizes, int n_in,
                              void* d_out, int out_size, void* d_ws, size_t ws_size,
                              hipStream_t stream)
{
    const float4* A = (const float4*)d_in[0];
    const float4* B = (const float4*)d_in[1];
    int n = in_sizes[0] / 4;             // rows
    float* out = (float*)d_out;
    float* out_gt = out;                 // first output [N]
    float* out_eq = out + n;             // second output [N]

    int block = 256;
    int grid = (n + block - 1) / block;
    cmp4_kernel<<<grid, block, 0, stream>>>(A, B, out_gt, out_eq, n);
}